// Round 4
// baseline (401.237 us; speedup 1.0000x reference)
//
#include <hip/hip_runtime.h>
#include <hip/hip_bf16.h>

// Problem: B=2,S=8192 -> TOK=16384 tokens; H=1024; DFF=4096.
// out[t] = mask[t] ? relu((h[t]*w[t]) @ W1 + b1) @ W2 + b2 : 0
// R8: R7 (8-phase counted-vmcnt gemm1) hardened after a container-level
//     failure: hipFuncSetAttribute moved OUT of kernel_launch (graph capture
//     tripwire, Guideline 9) into a library constructor; CFENCE after every
//     barrier. Schedule logic unchanged: 512 thr / 8 waves (2Mx4N), BK=64,
//     128 KiB dbuf LDS, stage order [A0,B0,B1,A1], vmcnt(6) P1-P3, last tile
//     drains 4->2->0. gemm2 stays R6's 64x128 single-buffer (106.8us).

#define TOK 16384
#define HID 1024
#define FF  4096

typedef __attribute__((ext_vector_type(8))) __bf16 bf16x8;
typedef __attribute__((ext_vector_type(4))) float f32x4;

#define VMW(n) asm volatile("s_waitcnt vmcnt(" #n ")" ::: "memory")
#define CFENCE() asm volatile("" ::: "memory")

__device__ __forceinline__ void gload_lds16(const void* g, void* l) {
  // async global->LDS, 16B per lane; LDS dest = wave-uniform base + lane*16
  __builtin_amdgcn_global_load_lds((const __attribute__((address_space(1))) void*)g,
                                   (__attribute__((address_space(3))) void*)l, 16, 0, 0);
}

// ---------------- weight transpose + fp32->bf16 cast ----------------
__global__ __launch_bounds__(256) void k_transpose(const float* __restrict__ src,
                                                   __hip_bfloat16* __restrict__ dst,
                                                   int R, int C) {
  __shared__ float tile[32][33];
  const int c0 = blockIdx.x * 32, r0 = blockIdx.y * 32;
  const int tx = threadIdx.x, ty = threadIdx.y;
#pragma unroll
  for (int i = 0; i < 32; i += 8)
    tile[ty + i][tx] = src[(size_t)(r0 + ty + i) * C + (c0 + tx)];
  __syncthreads();
#pragma unroll
  for (int i = 0; i < 32; i += 8)
    dst[(size_t)(c0 + ty + i) * R + (r0 + tx)] = __float2bfloat16(tile[tx][ty + i]);
}

// ---------------- gate + compact + zero dropped rows ----------------
#define GTOK 16
__global__ __launch_bounds__(256) void k_gate(const float* __restrict__ h,
                                              const float* __restrict__ wg,
                                              const float* __restrict__ bgp,
                                              const int* __restrict__ labels,
                                              float* __restrict__ out,
                                              __hip_bfloat16* __restrict__ A,
                                              int* __restrict__ idx,
                                              int* __restrict__ cnt) {
  const int tid = threadIdx.x;
  const int wave = tid >> 6, lane = tid & 63;
  const int t0 = blockIdx.x * GTOK;

  float4 gv[4];
#pragma unroll
  for (int it = 0; it < 4; ++it) gv[it] = ((const float4*)wg)[it * 64 + lane];

  __shared__ float slogit[GTOK];
  __shared__ int sslot[GTOK];

#pragma unroll
  for (int r = 0; r < 4; ++r) {
    const int li = r * 4 + wave;
    const float* hrow = h + (size_t)(t0 + li) * HID;
    float d = 0.f;
#pragma unroll
    for (int it = 0; it < 4; ++it) {
      const float4 hv = ((const float4*)hrow)[it * 64 + lane];
      d += hv.x * gv[it].x + hv.y * gv[it].y + hv.z * gv[it].z + hv.w * gv[it].w;
    }
#pragma unroll
    for (int o = 32; o > 0; o >>= 1) d += __shfl_down(d, o, 64);
    if (lane == 0) slogit[li] = d;
  }
  __syncthreads();

  if (tid == 0) {
    const float bg = bgp[0];
    int slots[GTOK];
    int n = 0;
#pragma unroll
    for (int li = 0; li < GTOK; ++li) {
      const bool keep = (slogit[li] + bg >= 0.0f) || (labels[t0 + li] == -100);
      slots[li] = keep ? n++ : -1;
    }
    const int base = atomicAdd(cnt, n);
#pragma unroll
    for (int li = 0; li < GTOK; ++li)
      sslot[li] = slots[li] >= 0 ? base + slots[li] : -1;
  }
  __syncthreads();

#pragma unroll
  for (int r = 0; r < 4; ++r) {
    const int li = r * 4 + wave;
    const int t = t0 + li;
    const int m = sslot[li];
    const float* hrow = h + (size_t)t * HID;
    if (m >= 0) {
      if (lane == 0) idx[m] = t;
      const float logit = slogit[li] + bgp[0];
      const float w = 1.0f / (1.0f + __expf(-logit));
#pragma unroll
      for (int it = 0; it < 4; ++it) {
        const float4 hv = ((const float4*)hrow)[it * 64 + lane];
        union { ushort4 u; __hip_bfloat16 b[4]; } pk;
        pk.b[0] = __float2bfloat16(hv.x * w);
        pk.b[1] = __float2bfloat16(hv.y * w);
        pk.b[2] = __float2bfloat16(hv.z * w);
        pk.b[3] = __float2bfloat16(hv.w * w);
        ((ushort4*)(A + (size_t)m * HID))[it * 64 + lane] = pk.u;
      }
    } else {
      const float4 z = make_float4(0.f, 0.f, 0.f, 0.f);
#pragma unroll
      for (int it = 0; it < 4; ++it)
        ((float4*)(out + (size_t)t * HID))[it * 64 + lane] = z;
    }
  }
}

// ---------------- GEMM swizzle (both GEMMs) ----------------
// LDS rows of 64 k-elems (128 B). Staging: lane l covers row
// r = wbase + c*8 + (l>>3), source chunk g = (l&7) ^ (r&7), stored at
// position l&7. Read of chunk ck of row r at position ck ^ (r&7); fragment
// rows have r&7 == fm&7 -> per-quad lanes cover all 8 bank-quads (2-way
// aliasing = free; measured 0 conflicts).

// GEMM1: Act = relu(A @ W1t^T + b1), bf16 out. K=HID=1024.
// 256x256 tile, 8 waves (2Mx4N), BK=64, double-buffered 128 KiB LDS,
// 8-phase counted-vmcnt schedule. Per-wave output: rows {hm*128+W*64+[0,64)}
// x cols {hn*128+wn*32+[0,32)}; acc[8][4], m=(hm*4+fi), n=(hn*2+fj).
__global__ __launch_bounds__(512, 2) void k_gemm1(const __hip_bfloat16* __restrict__ A,
                                                  const __hip_bfloat16* __restrict__ Bt,
                                                  const float* __restrict__ bias,
                                                  __hip_bfloat16* __restrict__ Act,
                                                  const int* __restrict__ cnt) {
  extern __shared__ char sm[];  // [buf:2][op:2][half:2][128*64 bf16] = 128 KiB
  const int Mc = *cnt;
  const int m0 = blockIdx.x * 256;
  if (m0 >= Mc) return;
  const int n0 = blockIdx.y * 256;

  const int tid = threadIdx.x;
  const int wid = tid >> 6, lane = tid & 63;
  const int W = wid >> 2;        // M-group 0..1
  const int wn = wid & 3;        // N-group 0..3
  const int fm = lane & 15, quad = lane >> 4;
  const int srow8 = lane >> 3;
  const int sg = ((lane & 7) ^ srow8) * 8;

  const __hip_bfloat16* gA0 = A  + (size_t)(m0 + wid * 16 + srow8) * HID + sg;
  const __hip_bfloat16* gB0 = Bt + (size_t)(n0 + wid * 16 + srow8) * HID + sg;
  const int ldsw = wid * 2048;   // wave's 16-row slice within a 16 KiB half

  f32x4 acc[8][4] = {};

  auto stage = [&](int nbuf, int op, int h, int kt) {
    const __hip_bfloat16* g = (op == 0 ? gA0 : gB0) + (size_t)(h * 128) * HID + kt;
    char* d = sm + nbuf * 65536 + op * 32768 + h * 16384 + ldsw;
#pragma unroll
    for (int c = 0; c < 2; ++c)
      gload_lds16(g + (size_t)(c * 8) * HID, d + c * 1024);
  };
  auto readA = [&](int buf, int hm, bf16x8* a) {
    const __hip_bfloat16* p = (const __hip_bfloat16*)(sm + buf * 65536 + hm * 16384);
#pragma unroll
    for (int fi = 0; fi < 4; ++fi)
#pragma unroll
      for (int ks = 0; ks < 2; ++ks)
        a[fi * 2 + ks] = *(const bf16x8*)&p[(W * 64 + fi * 16 + fm) * 64 +
                                            (((ks * 4 + quad) ^ (fm & 7)) * 8)];
  };
  auto readB = [&](int buf, int hn, bf16x8* b) {
    const __hip_bfloat16* p = (const __hip_bfloat16*)(sm + buf * 65536 + 32768 + hn * 16384);
#pragma unroll
    for (int fj = 0; fj < 2; ++fj)
#pragma unroll
      for (int ks = 0; ks < 2; ++ks)
        b[fj * 2 + ks] = *(const bf16x8*)&p[(wn * 32 + fj * 16 + fm) * 64 +
                                            (((ks * 4 + quad) ^ (fm & 7)) * 8)];
  };
  auto mma = [&](const bf16x8* a, const bf16x8* b, int mb, int nb) {
    __builtin_amdgcn_s_setprio(1);
#pragma unroll
    for (int fi = 0; fi < 4; ++fi)
#pragma unroll
      for (int fj = 0; fj < 2; ++fj)
#pragma unroll
        for (int ks = 0; ks < 2; ++ks)
          acc[mb + fi][nb + fj] = __builtin_amdgcn_mfma_f32_16x16x32_bf16(
              a[fi * 2 + ks], b[fj * 2 + ks], acc[mb + fi][nb + fj], 0, 0, 0);
    __builtin_amdgcn_s_setprio(0);
  };

  // prologue: tile 0 -> buf 0, staging order [A0, B0, B1, A1]
  stage(0, 0, 0, 0);
  stage(0, 1, 0, 0);
  stage(0, 1, 1, 0);
  stage(0, 0, 1, 0);

  bf16x8 a0[8], a1[8], b0[4], b1[4];
  const int NT = HID / 64;
  for (int t = 0; t < NT; ++t) {
    const int buf = t & 1, nbuf = buf ^ 1;
    const bool pf = (t + 1) < NT;
    const int ktn = (t + 1) * 64;
    // P1: needs A0,B0 of tile t (4 oldest loads in this wave's FIFO)
    if (pf) { stage(nbuf, 0, 0, ktn); VMW(6); } else { VMW(4); }
    __builtin_amdgcn_s_barrier(); CFENCE();
    readA(buf, 0, a0); readB(buf, 0, b0);
    mma(a0, b0, 0, 0);
    __builtin_amdgcn_s_barrier(); CFENCE();
    // P2: needs B1 of tile t
    if (pf) { stage(nbuf, 1, 0, ktn); VMW(6); } else { VMW(2); }
    __builtin_amdgcn_s_barrier(); CFENCE();
    readB(buf, 1, b1);
    mma(a0, b1, 0, 2);
    __builtin_amdgcn_s_barrier(); CFENCE();
    // P3: needs A1 of tile t
    if (pf) { stage(nbuf, 1, 1, ktn); VMW(6); } else { VMW(0); }
    __builtin_amdgcn_s_barrier(); CFENCE();
    readA(buf, 1, a1);
    mma(a1, b1, 4, 2);
    __builtin_amdgcn_s_barrier(); CFENCE();
    // P4: no new frags (a1, b0 live); trailing barrier guards tile switch
    if (pf) { stage(nbuf, 0, 1, ktn); }
    mma(a1, b0, 4, 0);
    __builtin_amdgcn_s_barrier(); CFENCE();
  }

#pragma unroll
  for (int n = 0; n < 4; ++n) {
    const int col = n0 + (n >> 1) * 128 + wn * 32 + (n & 1) * 16 + fm;
    const float bv = bias[col];
#pragma unroll
    for (int m = 0; m < 8; ++m) {
      const int rbase = m0 + (m >> 2) * 128 + W * 64 + (m & 3) * 16 + quad * 4;
#pragma unroll
      for (int r = 0; r < 4; ++r) {
        float v = acc[m][n][r] + bv;
        v = v > 0.f ? v : 0.f;
        Act[(size_t)(rbase + r) * FF + col] = __float2bfloat16(v);
      }
    }
  }
}

// GEMM2: out[idx[m]] = Act @ W2t^T + b2, fp32 scatter. K=FF=4096.
// BM=64 x BN=128, single-buffered (R6: 106.8us, ~715 TF; N=1024 too small
// for the 256^2 template). ~1144 active blocks, 24 KiB LDS.
__global__ __launch_bounds__(256, 4) void k_gemm2(const __hip_bfloat16* __restrict__ Act,
                                                  const __hip_bfloat16* __restrict__ Bt,
                                                  const float* __restrict__ bias,
                                                  const int* __restrict__ idx,
                                                  float* __restrict__ out,
                                                  const int* __restrict__ cnt) {
  const int Mc = *cnt;
  const int m0 = blockIdx.x * 64;
  if (m0 >= Mc) return;
  const int n0 = blockIdx.y * 128;

  __shared__ __hip_bfloat16 lA[64 * 64];   // 8 KiB
  __shared__ __hip_bfloat16 lB[128 * 64];  // 16 KiB

  const int tid = threadIdx.x;
  const int wave = tid >> 6, lane = tid & 63;
  const int wr = (wave >> 1) * 32, wc = (wave & 1) * 64;
  const int fm = lane & 15, quad = lane >> 4;
  const int srow = (lane >> 3);
  const int sg   = ((lane & 7) ^ srow) * 8;

  f32x4 acc[2][4] = {};

  const __hip_bfloat16* gA = Act + (size_t)(m0 + wave * 16 + srow) * FF + sg;
  const __hip_bfloat16* gB = Bt  + (size_t)(n0 + wave * 32 + srow) * FF + sg;
  char* dA = (char*)lA + wave * 2048;
  char* dB = (char*)lB + wave * 4096;

  for (int kt = 0; kt < FF; kt += 64) {
    __syncthreads();
#pragma unroll
    for (int c = 0; c < 2; ++c)
      gload_lds16(gA + (size_t)(c * 8) * FF + kt, dA + c * 1024);
#pragma unroll
    for (int c = 0; c < 4; ++c)
      gload_lds16(gB + (size_t)(c * 8) * FF + kt, dB + c * 1024);
    __syncthreads();
#pragma unroll
    for (int ks = 0; ks < 2; ++ks) {
      bf16x8 af[2], bb[4];
#pragma unroll
      for (int i = 0; i < 2; ++i)
        af[i] = *(const bf16x8*)&lA[(wr + i * 16 + fm) * 64 + (((ks * 4 + quad) ^ (fm & 7)) * 8)];
#pragma unroll
      for (int j = 0; j < 4; ++j)
        bb[j] = *(const bf16x8*)&lB[(wc + j * 16 + fm) * 64 + (((ks * 4 + quad) ^ (fm & 7)) * 8)];
#pragma unroll
      for (int i = 0; i < 2; ++i)
#pragma unroll
        for (int j = 0; j < 4; ++j)
          acc[i][j] = __builtin_amdgcn_mfma_f32_16x16x32_bf16(af[i], bb[j], acc[i][j], 0, 0, 0);
    }
  }

#pragma unroll
  for (int i = 0; i < 2; ++i) {
#pragma unroll
    for (int r = 0; r < 4; ++r) {
      const int m = m0 + wr + i * 16 + quad * 4 + r;
      if (m < Mc) {
        const int t = idx[m];
        float* orow = out + (size_t)t * HID + n0 + wc + fm;
#pragma unroll
        for (int j = 0; j < 4; ++j)
          orow[j * 16] = acc[i][j][r] + bias[n0 + wc + j * 16 + fm];
      }
    }
  }
}

// ---------------- one-time setup at library load (OUTSIDE graph capture) ----
__attribute__((constructor)) static void _athena_setup() {
  // allow 128 KiB dynamic LDS for k_gemm1; ignore error (launch will surface it)
  (void)hipFuncSetAttribute(reinterpret_cast<const void*>(k_gemm1),
                            hipFuncAttributeMaxDynamicSharedMemorySize, 131072);
}

// ---------------- launch ----------------
extern "C" void kernel_launch(void* const* d_in, const int* in_sizes, int n_in,
                              void* d_out, int out_size, void* d_ws, size_t ws_size,
                              hipStream_t stream) {
  const float* h   = (const float*)d_in[0];
  const float* Wg  = (const float*)d_in[3];
  const float* bg  = (const float*)d_in[4];
  const float* W1  = (const float*)d_in[5];
  const float* b1  = (const float*)d_in[6];
  const float* W2  = (const float*)d_in[7];
  const float* b2  = (const float*)d_in[8];
  const int*  labels = (const int*)d_in[9];
  float* out = (float*)d_out;

  char* ws = (char*)d_ws;
  int* cnt            = (int*)(ws + 0);
  int* idx            = (int*)(ws + 1024);
  __hip_bfloat16* W1t = (__hip_bfloat16*)(ws + (1u  << 17));   // [FF][HID]
  __hip_bfloat16* W2t = (__hip_bfloat16*)(ws + (16u << 20));   // [HID][FF]
  __hip_bfloat16* A   = (__hip_bfloat16*)(ws + (32u << 20));   // [TOK][HID]
  __hip_bfloat16* Act = (__hip_bfloat16*)(ws + (64ull << 20)); // [TOK][FF]

  hipMemsetAsync(cnt, 0, 4, stream);
  k_transpose<<<dim3(FF / 32, HID / 32), dim3(32, 8), 0, stream>>>(W1, W1t, HID, FF);
  k_transpose<<<dim3(HID / 32, FF / 32), dim3(32, 8), 0, stream>>>(W2, W2t, FF, HID);
  k_gate<<<TOK / GTOK, 256, 0, stream>>>(h, Wg, bg, labels, out, A, idx, cnt);
  k_gemm1<<<dim3(TOK / 256, FF / 256), 512, 131072, stream>>>(A, W1t, b1, Act, cnt);
  k_gemm2<<<dim3(TOK / 64, HID / 128), 256, 0, stream>>>(Act, W2t, b2, idx, out, cnt);
}

// Round 5
// 368.223 us; speedup vs baseline: 1.0897x; 1.0897x over previous
//
#include <hip/hip_runtime.h>
#include <hip/hip_bf16.h>

// Problem: B=2,S=8192 -> TOK=16384 tokens; H=1024; DFF=4096.
// out[t] = mask[t] ? relu((h[t]*w[t]) @ W1 + b1) @ W2 + b2 : 0
// R9: gemm1 8-phase REVERTED (R8: 125us vs R6's ~100 — packing math: 576
//     active blocks at 1 block/CU = 3 quantized rounds = 1.33x floor; plus
//     ds_read-after-barrier put LDS latency on the MFMA critical path).
//     Back to R6's 128^2 2-barrier gemm1 (~770 TF, 9 blocks/CU).
//     NEW: transposes + gate fused into ONE dispatch (k_pre) — the three
//     memory-bound phases overlap instead of serializing; gate keeps h in
//     registers across passes (no 67MB re-read). gemm2 stays R6 64x128.

#define TOK 16384
#define HID 1024
#define FF  4096

typedef __attribute__((ext_vector_type(8))) __bf16 bf16x8;
typedef __attribute__((ext_vector_type(4))) float f32x4;

__device__ __forceinline__ void gload_lds16(const void* g, void* l) {
  // async global->LDS, 16B per lane; LDS dest = wave-uniform base + lane*16
  __builtin_amdgcn_global_load_lds((const __attribute__((address_space(1))) void*)g,
                                   (__attribute__((address_space(3))) void*)l, 16, 0, 0);
}

// ---------------- fused pre-pass: W1^T, W2^T, gate+compact ----------------
// Block ranges: [0,1024) transpose W1 (64x64 tiles), [1024,2048) transpose W2,
// [2048,3072) gate (16 tokens/block). One dispatch -> phases overlap on-chip.
#define GTOK 16
#define NBT1 1024  // (FF/64)*(HID/64)
#define NBT2 1024  // (HID/64)*(FF/64)

__global__ __launch_bounds__(256) void k_pre(const float* __restrict__ W1,
                                             __hip_bfloat16* __restrict__ W1t,
                                             const float* __restrict__ W2,
                                             __hip_bfloat16* __restrict__ W2t,
                                             const float* __restrict__ h,
                                             const float* __restrict__ wg,
                                             const float* __restrict__ bgp,
                                             const int* __restrict__ labels,
                                             float* __restrict__ out,
                                             __hip_bfloat16* __restrict__ A,
                                             int* __restrict__ idx,
                                             int* __restrict__ cnt) {
  const int bid = blockIdx.x;
  const int tid = threadIdx.x;

  if (bid < NBT1 + NBT2) {
    // -------- transpose: src[R][C] fp32 -> dst[C][R] bf16 --------
    const float* src;
    __hip_bfloat16* dst;
    int R, C, tb;
    if (bid < NBT1) { src = W1; dst = W1t; R = HID; C = FF;  tb = bid; }
    else            { src = W2; dst = W2t; R = FF;  C = HID; tb = bid - NBT1; }
    const int nbc = C / 64;
    const int c0 = (tb % nbc) * 64, r0 = (tb / nbc) * 64;
    __shared__ float tile[64][65];        // stride 65: conflict-free col reads
    const int tx = tid & 63, ty = tid >> 6;
#pragma unroll
    for (int i = 0; i < 16; ++i)
      tile[ty + i * 4][tx] = src[(size_t)(r0 + ty + i * 4) * C + (c0 + tx)];
    __syncthreads();
#pragma unroll
    for (int i = 0; i < 16; ++i)
      dst[(size_t)(c0 + ty + i * 4) * R + (r0 + tx)] =
          __float2bfloat16(tile[tx][ty + i * 4]);
    return;
  }

  // -------- gate + compact + zero dropped rows --------
  const int gb = bid - (NBT1 + NBT2);
  const int t0 = gb * GTOK;
  const int wave = tid >> 6, lane = tid & 63;

  float4 gv[4];
#pragma unroll
  for (int it = 0; it < 4; ++it) gv[it] = ((const float4*)wg)[it * 64 + lane];

  // hold h rows in registers across both passes (64 VGPR)
  float4 hv[4][4];
  __shared__ float slogit[GTOK];
  __shared__ int sslot[GTOK];

#pragma unroll
  for (int r = 0; r < 4; ++r) {
    const int li = r * 4 + wave;
    const float* hrow = h + (size_t)(t0 + li) * HID;
    float d = 0.f;
#pragma unroll
    for (int it = 0; it < 4; ++it) {
      hv[r][it] = ((const float4*)hrow)[it * 64 + lane];
      d += hv[r][it].x * gv[it].x + hv[r][it].y * gv[it].y +
           hv[r][it].z * gv[it].z + hv[r][it].w * gv[it].w;
    }
#pragma unroll
    for (int o = 32; o > 0; o >>= 1) d += __shfl_down(d, o, 64);
    if (lane == 0) slogit[li] = d;
  }
  __syncthreads();

  if (tid == 0) {  // prefix over 16 keep flags; ONE atomic per block
    const float bg = bgp[0];
    int slots[GTOK];
    int n = 0;
#pragma unroll
    for (int li = 0; li < GTOK; ++li) {
      const bool keep = (slogit[li] + bg >= 0.0f) || (labels[t0 + li] == -100);
      slots[li] = keep ? n++ : -1;
    }
    const int base = atomicAdd(cnt, n);
#pragma unroll
    for (int li = 0; li < GTOK; ++li)
      sslot[li] = slots[li] >= 0 ? base + slots[li] : -1;
  }
  __syncthreads();

#pragma unroll
  for (int r = 0; r < 4; ++r) {
    const int li = r * 4 + wave;
    const int t = t0 + li;
    const int m = sslot[li];
    if (m >= 0) {
      if (lane == 0) idx[m] = t;
      const float logit = slogit[li] + bgp[0];
      const float w = 1.0f / (1.0f + __expf(-logit));
#pragma unroll
      for (int it = 0; it < 4; ++it) {
        union { ushort4 u; __hip_bfloat16 b[4]; } pk;
        pk.b[0] = __float2bfloat16(hv[r][it].x * w);
        pk.b[1] = __float2bfloat16(hv[r][it].y * w);
        pk.b[2] = __float2bfloat16(hv[r][it].z * w);
        pk.b[3] = __float2bfloat16(hv[r][it].w * w);
        ((ushort4*)(A + (size_t)m * HID))[it * 64 + lane] = pk.u;
      }
    } else {
      const float4 z = make_float4(0.f, 0.f, 0.f, 0.f);
#pragma unroll
      for (int it = 0; it < 4; ++it)
        ((float4*)(out + (size_t)t * HID))[it * 64 + lane] = z;
    }
  }
}

// ---------------- GEMM swizzle (both GEMMs) ----------------
// LDS rows of 64 k-elems (128 B). Staging: lane l covers row
// r = wbase + c*8 + (l>>3), source chunk g = (l&7) ^ (r&7), stored at
// position l&7. Read of chunk ck of row r at position ck ^ (r&7); fragment
// rows have r&7 == fm&7 -> per-quad lanes cover all 8 bank-quads (2-way
// aliasing = free; measured 0 conflicts).

// GEMM1: Act = relu(A @ W1t^T + b1), bf16 out. K=HID=1024. 128x128 tile,
// single-buffered: 2304 active blocks (~9/CU) -> cross-block overlap covers
// the global->LDS latency (R6-proven structure).
__global__ __launch_bounds__(256, 2) void k_gemm1(const __hip_bfloat16* __restrict__ A,
                                                  const __hip_bfloat16* __restrict__ Bt,
                                                  const float* __restrict__ bias,
                                                  __hip_bfloat16* __restrict__ Act,
                                                  const int* __restrict__ cnt) {
  const int Mc = *cnt;
  const int m0 = blockIdx.x * 128;
  if (m0 >= Mc) return;
  const int n0 = blockIdx.y * 128;

  __shared__ __hip_bfloat16 lA[128 * 64];  // 16 KiB
  __shared__ __hip_bfloat16 lB[128 * 64];  // 16 KiB

  const int tid = threadIdx.x;
  const int wave = tid >> 6, lane = tid & 63;
  const int wr = (wave >> 1) * 64, wc = (wave & 1) * 64;
  const int fm = lane & 15, quad = lane >> 4;

  const int srow = (lane >> 3);                       // 0..7
  const int sg   = ((lane & 7) ^ srow) * 8;           // global elem offset

  f32x4 acc[4][4] = {};

  const __hip_bfloat16* gA = A  + (size_t)(m0 + wave * 32 + srow) * HID + sg;
  const __hip_bfloat16* gB = Bt + (size_t)(n0 + wave * 32 + srow) * HID + sg;
  char* dA = (char*)lA + wave * 4096;
  char* dB = (char*)lB + wave * 4096;

  for (int kt = 0; kt < HID; kt += 64) {
    __syncthreads();
#pragma unroll
    for (int c = 0; c < 4; ++c) {
      gload_lds16(gA + (size_t)(c * 8) * HID + kt, dA + c * 1024);
      gload_lds16(gB + (size_t)(c * 8) * HID + kt, dB + c * 1024);
    }
    __syncthreads();
#pragma unroll
    for (int ks = 0; ks < 2; ++ks) {
      bf16x8 af[4], bb[4];
#pragma unroll
      for (int i = 0; i < 4; ++i)
        af[i] = *(const bf16x8*)&lA[(wr + i * 16 + fm) * 64 + (((ks * 4 + quad) ^ (fm & 7)) * 8)];
#pragma unroll
      for (int j = 0; j < 4; ++j)
        bb[j] = *(const bf16x8*)&lB[(wc + j * 16 + fm) * 64 + (((ks * 4 + quad) ^ (fm & 7)) * 8)];
#pragma unroll
      for (int i = 0; i < 4; ++i)
#pragma unroll
        for (int j = 0; j < 4; ++j)
          acc[i][j] = __builtin_amdgcn_mfma_f32_16x16x32_bf16(af[i], bb[j], acc[i][j], 0, 0, 0);
    }
  }

#pragma unroll
  for (int j = 0; j < 4; ++j) {
    const int col = n0 + wc + j * 16 + fm;
    const float bv = bias[col];
#pragma unroll
    for (int i = 0; i < 4; ++i) {
      const int rbase = m0 + wr + i * 16 + quad * 4;
#pragma unroll
      for (int r = 0; r < 4; ++r) {
        float v = acc[i][j][r] + bv;
        v = v > 0.f ? v : 0.f;
        Act[(size_t)(rbase + r) * FF + col] = __float2bfloat16(v);
      }
    }
  }
}

// GEMM2: out[idx[m]] = Act @ W2t^T + b2, fp32 scatter. K=FF=4096.
// BM=64 x BN=128, single-buffered (R6: 106.8us, ~720 TF). ~1144 active
// blocks (4.5/CU), 24 KiB LDS.
__global__ __launch_bounds__(256, 4) void k_gemm2(const __hip_bfloat16* __restrict__ Act,
                                                  const __hip_bfloat16* __restrict__ Bt,
                                                  const float* __restrict__ bias,
                                                  const int* __restrict__ idx,
                                                  float* __restrict__ out,
                                                  const int* __restrict__ cnt) {
  const int Mc = *cnt;
  const int m0 = blockIdx.x * 64;
  if (m0 >= Mc) return;
  const int n0 = blockIdx.y * 128;

  __shared__ __hip_bfloat16 lA[64 * 64];   // 8 KiB
  __shared__ __hip_bfloat16 lB[128 * 64];  // 16 KiB

  const int tid = threadIdx.x;
  const int wave = tid >> 6, lane = tid & 63;
  const int wr = (wave >> 1) * 32, wc = (wave & 1) * 64;
  const int fm = lane & 15, quad = lane >> 4;
  const int srow = (lane >> 3);
  const int sg   = ((lane & 7) ^ srow) * 8;

  f32x4 acc[2][4] = {};

  const __hip_bfloat16* gA = Act + (size_t)(m0 + wave * 16 + srow) * FF + sg;
  const __hip_bfloat16* gB = Bt  + (size_t)(n0 + wave * 32 + srow) * FF + sg;
  char* dA = (char*)lA + wave * 2048;
  char* dB = (char*)lB + wave * 4096;

  for (int kt = 0; kt < FF; kt += 64) {
    __syncthreads();
#pragma unroll
    for (int c = 0; c < 2; ++c)
      gload_lds16(gA + (size_t)(c * 8) * FF + kt, dA + c * 1024);
#pragma unroll
    for (int c = 0; c < 4; ++c)
      gload_lds16(gB + (size_t)(c * 8) * FF + kt, dB + c * 1024);
    __syncthreads();
#pragma unroll
    for (int ks = 0; ks < 2; ++ks) {
      bf16x8 af[2], bb[4];
#pragma unroll
      for (int i = 0; i < 2; ++i)
        af[i] = *(const bf16x8*)&lA[(wr + i * 16 + fm) * 64 + (((ks * 4 + quad) ^ (fm & 7)) * 8)];
#pragma unroll
      for (int j = 0; j < 4; ++j)
        bb[j] = *(const bf16x8*)&lB[(wc + j * 16 + fm) * 64 + (((ks * 4 + quad) ^ (fm & 7)) * 8)];
#pragma unroll
      for (int i = 0; i < 2; ++i)
#pragma unroll
        for (int j = 0; j < 4; ++j)
          acc[i][j] = __builtin_amdgcn_mfma_f32_16x16x32_bf16(af[i], bb[j], acc[i][j], 0, 0, 0);
    }
  }

#pragma unroll
  for (int i = 0; i < 2; ++i) {
#pragma unroll
    for (int r = 0; r < 4; ++r) {
      const int m = m0 + wr + i * 16 + quad * 4 + r;
      if (m < Mc) {
        const int t = idx[m];
        float* orow = out + (size_t)t * HID + n0 + wc + fm;
#pragma unroll
        for (int j = 0; j < 4; ++j)
          orow[j * 16] = acc[i][j][r] + bias[n0 + wc + j * 16 + fm];
      }
    }
  }
}

// ---------------- launch ----------------
extern "C" void kernel_launch(void* const* d_in, const int* in_sizes, int n_in,
                              void* d_out, int out_size, void* d_ws, size_t ws_size,
                              hipStream_t stream) {
  const float* h   = (const float*)d_in[0];
  const float* Wg  = (const float*)d_in[3];
  const float* bg  = (const float*)d_in[4];
  const float* W1  = (const float*)d_in[5];
  const float* b1  = (const float*)d_in[6];
  const float* W2  = (const float*)d_in[7];
  const float* b2  = (const float*)d_in[8];
  const int*  labels = (const int*)d_in[9];
  float* out = (float*)d_out;

  char* ws = (char*)d_ws;
  int* cnt            = (int*)(ws + 0);
  int* idx            = (int*)(ws + 1024);
  __hip_bfloat16* W1t = (__hip_bfloat16*)(ws + (1u  << 17));   // [FF][HID]
  __hip_bfloat16* W2t = (__hip_bfloat16*)(ws + (16u << 20));   // [HID][FF]
  __hip_bfloat16* A   = (__hip_bfloat16*)(ws + (32u << 20));   // [TOK][HID]
  __hip_bfloat16* Act = (__hip_bfloat16*)(ws + (64ull << 20)); // [TOK][FF]

  hipMemsetAsync(cnt, 0, 4, stream);
  k_pre<<<NBT1 + NBT2 + TOK / GTOK, 256, 0, stream>>>(W1, W1t, W2, W2t, h, Wg,
                                                      bg, labels, out, A, idx, cnt);
  k_gemm1<<<dim3(TOK / 128, FF / 128), 256, 0, stream>>>(A, W1t, b1, Act, cnt);
  k_gemm2<<<dim3(TOK / 64, HID / 128), 256, 0, stream>>>(Act, W2t, b2, idx, out, cnt);
}